// Round 1
// baseline (17161.391 us; speedup 1.0000x reference)
//
#include <hip/hip_runtime.h>
#include <cstdint>

// WeatherSTGNN persistent kernel.
// One block = one batch element, looping all 48 encoder + 48 decoder steps.
// All weights staged in LDS (W_ih/W_hh as packed bf16 pairs -> 64KB), hx double-
// buffered in LDS, cx in registers (fixed thread->(node,4h) ownership).
// LDS total ~153KB -> 1 block/CU, 512 threads = 2 waves/SIMD.

#define NT 512
#define TSTEPS 48
#define FUT 48
#define SR 68    // padded stride for 32x64 activation tiles (float4-aligned, conflict-free)
#define DSR 33   // stride for 32x32 decoder hidden

__device__ __forceinline__ float sigm(float x) { return 1.0f / (1.0f + __expf(-x)); }
__device__ __forceinline__ float tanh_fast(float x) { return 1.0f - 2.0f / (__expf(2.0f * x) + 1.0f); }
__device__ __forceinline__ float bflo(unsigned u) { return __uint_as_float(u << 16); }
__device__ __forceinline__ float bfhi(unsigned u) { return __uint_as_float(u & 0xffff0000u); }

__device__ __forceinline__ unsigned bf2pack(float a, float b) {
  unsigned ua = __float_as_uint(a);
  ua = (ua + 0x7fffu + ((ua >> 16) & 1u)) >> 16;
  unsigned ub = __float_as_uint(b);
  ub = (ub + 0x7fffu + ((ub >> 16) & 1u)) >> 16;
  return (ua & 0xffffu) | (ub << 16);
}

__global__ __launch_bounds__(NT, 1)
void stgnn_kernel(const float* __restrict__ xh, const float* __restrict__ adj,
                  const float* __restrict__ Wenc, const float* __restrict__ benc,
                  const float* __restrict__ Wg1, const float* __restrict__ bg1,
                  const float* __restrict__ Wg2, const float* __restrict__ bg2,
                  const float* __restrict__ Wih, const float* __restrict__ Whh,
                  const float* __restrict__ bih, const float* __restrict__ bhh,
                  const float* __restrict__ Wd1, const float* __restrict__ bd1,
                  const float* __restrict__ Wd2, const float* __restrict__ bd2,
                  float* __restrict__ out) {
  __shared__ __align__(16) float sWenc[11 * 64];
  __shared__ __align__(16) float sBenc[64];
  __shared__ __align__(16) float sWg1[64 * 64];
  __shared__ __align__(16) float sBg1[64];
  __shared__ __align__(16) float sWg2[64 * 64];
  __shared__ __align__(16) float sBg2[64];
  __shared__ __align__(16) float sAhat[32 * 32];
  __shared__ __align__(16) unsigned sWcat[64 * 256];  // [kk][c] bf16x2: k<64 -> Wih, k>=64 -> Whh
  __shared__ __align__(16) float sBih[256];
  __shared__ __align__(16) float sWd1[64 * 32];
  __shared__ __align__(16) float sBd1[32];
  __shared__ __align__(16) float sWd2[32 * 6];
  __shared__ __align__(16) float sBd2[8];
  __shared__ float sDeg[32];
  __shared__ __align__(16) float sX[32 * 12];      // current input (pred|stat in decoder)
  __shared__ __align__(16) float sA[32 * SR];
  __shared__ __align__(16) float sB[32 * SR];
  __shared__ __align__(16) float sH[2][32 * SR];   // double-buffered hidden state
  __shared__ __align__(16) float sD1[32 * DSR];

  const int tid = threadIdx.x;
  const int b = blockIdx.x;
  const int r = tid >> 4;           // node row 0..31 (fixed ownership)
  const int hb = (tid & 15) << 2;   // h base 0,4,...,60

  // ---------------- stage weights ----------------
  for (int i = tid; i < 11 * 64; i += NT) sWenc[i] = Wenc[i];
  for (int i = tid; i < 64; i += NT) { sBenc[i] = benc[i]; sBg1[i] = bg1[i]; sBg2[i] = bg2[i]; }
  for (int i = tid; i < 64 * 64; i += NT) { sWg1[i] = Wg1[i]; sWg2[i] = Wg2[i]; }
  for (int i = tid; i < 256; i += NT) sBih[i] = bih[i] + bhh[i];
  for (int i = tid; i < 64 * 32; i += NT) sWd1[i] = Wd1[i];
  for (int i = tid; i < 32; i += NT) sBd1[i] = bd1[i];
  for (int i = tid; i < 32 * 6; i += NT) sWd2[i] = Wd2[i];
  if (tid < 8) sBd2[tid] = (tid < 6) ? bd2[tid] : 0.0f;
  for (int i = tid; i < 64 * 256; i += NT) {
    int kk = i >> 8, c = i & 255;
    int k0 = kk * 2;
    float w0, w1;
    if (k0 < 64) { w0 = Wih[c * 64 + k0];      w1 = Wih[c * 64 + k0 + 1]; }
    else         { w0 = Whh[c * 64 + k0 - 64]; w1 = Whh[c * 64 + k0 - 63]; }
    sWcat[kk * 256 + c] = bf2pack(w0, w1);
  }
  if (tid < 32) {
    float s = 0.0f;
    for (int j = 0; j < 32; ++j) s += (j == tid) ? 1.0f : adj[tid * 32 + j];
    sDeg[tid] = 1.0f / sqrtf(fmaxf(s, 1.0f));
  }
  for (int i = tid; i < 2 * 32 * SR; i += NT) (&sH[0][0])[i] = 0.0f;
  __syncthreads();
  for (int i = tid; i < 32 * 32; i += NT) {
    int ii = i >> 5, jj = i & 31;
    float v = (ii == jj) ? 1.0f : adj[i];
    sAhat[i] = sDeg[ii] * v * sDeg[jj];
  }
  float cx[4] = {0.0f, 0.0f, 0.0f, 0.0f};
  __syncthreads();

  int cur = 0;
  for (int step = 0; step < TSTEPS + FUT; ++step) {
    const bool dec = (step >= TSTEPS);
    // ---- phase 1 (encoder only): load x_t ----
    if (!dec) {
      if (tid < 32 * 11) {
        int j = tid / 11, f = tid - j * 11;
        sX[j * 12 + f] = xh[(((long long)b * TSTEPS + step) * 32 + j) * 11 + f];
      }
      __syncthreads();
    }
    // ---- phase 2: enc = relu(x @ Wenc + benc) -> sA ----
    {
      float4 acc = *reinterpret_cast<const float4*>(&sBenc[hb]);
      #pragma unroll
      for (int k = 0; k < 11; ++k) {
        float x = sX[r * 12 + k];
        float4 w = *reinterpret_cast<const float4*>(&sWenc[k * 64 + hb]);
        acc.x += x * w.x; acc.y += x * w.y; acc.z += x * w.z; acc.w += x * w.w;
      }
      float4 o = make_float4(fmaxf(acc.x, 0.f), fmaxf(acc.y, 0.f), fmaxf(acc.z, 0.f), fmaxf(acc.w, 0.f));
      *reinterpret_cast<float4*>(&sA[r * SR + hb]) = o;
    }
    __syncthreads();
    // ---- phase 3: t1 = enc @ Wg1 -> sB ----
    {
      float4 acc = make_float4(0.f, 0.f, 0.f, 0.f);
      #pragma unroll 4
      for (int kk = 0; kk < 16; ++kk) {
        float4 xv = *reinterpret_cast<const float4*>(&sA[r * SR + 4 * kk]);
        float4 w0 = *reinterpret_cast<const float4*>(&sWg1[(4 * kk + 0) * 64 + hb]);
        float4 w1 = *reinterpret_cast<const float4*>(&sWg1[(4 * kk + 1) * 64 + hb]);
        float4 w2 = *reinterpret_cast<const float4*>(&sWg1[(4 * kk + 2) * 64 + hb]);
        float4 w3 = *reinterpret_cast<const float4*>(&sWg1[(4 * kk + 3) * 64 + hb]);
        acc.x += xv.x * w0.x + xv.y * w1.x + xv.z * w2.x + xv.w * w3.x;
        acc.y += xv.x * w0.y + xv.y * w1.y + xv.z * w2.y + xv.w * w3.y;
        acc.z += xv.x * w0.z + xv.y * w1.z + xv.z * w2.z + xv.w * w3.z;
        acc.w += xv.x * w0.w + xv.y * w1.w + xv.z * w2.w + xv.w * w3.w;
      }
      *reinterpret_cast<float4*>(&sB[r * SR + hb]) = acc;
    }
    __syncthreads();
    // ---- phase 4: s1 = relu(Ahat @ t1 + bg1) -> sA ----
    {
      float4 acc = *reinterpret_cast<const float4*>(&sBg1[hb]);
      #pragma unroll 8
      for (int p = 0; p < 32; ++p) {
        float a = sAhat[r * 32 + p];
        float4 tv = *reinterpret_cast<const float4*>(&sB[p * SR + hb]);
        acc.x += a * tv.x; acc.y += a * tv.y; acc.z += a * tv.z; acc.w += a * tv.w;
      }
      float4 o = make_float4(fmaxf(acc.x, 0.f), fmaxf(acc.y, 0.f), fmaxf(acc.z, 0.f), fmaxf(acc.w, 0.f));
      *reinterpret_cast<float4*>(&sA[r * SR + hb]) = o;
    }
    __syncthreads();
    // ---- phase 5: t2 = s1 @ Wg2 -> sB ----
    {
      float4 acc = make_float4(0.f, 0.f, 0.f, 0.f);
      #pragma unroll 4
      for (int kk = 0; kk < 16; ++kk) {
        float4 xv = *reinterpret_cast<const float4*>(&sA[r * SR + 4 * kk]);
        float4 w0 = *reinterpret_cast<const float4*>(&sWg2[(4 * kk + 0) * 64 + hb]);
        float4 w1 = *reinterpret_cast<const float4*>(&sWg2[(4 * kk + 1) * 64 + hb]);
        float4 w2 = *reinterpret_cast<const float4*>(&sWg2[(4 * kk + 2) * 64 + hb]);
        float4 w3 = *reinterpret_cast<const float4*>(&sWg2[(4 * kk + 3) * 64 + hb]);
        acc.x += xv.x * w0.x + xv.y * w1.x + xv.z * w2.x + xv.w * w3.x;
        acc.y += xv.x * w0.y + xv.y * w1.y + xv.z * w2.y + xv.w * w3.y;
        acc.z += xv.x * w0.z + xv.y * w1.z + xv.z * w2.z + xv.w * w3.z;
        acc.w += xv.x * w0.w + xv.y * w1.w + xv.z * w2.w + xv.w * w3.w;
      }
      *reinterpret_cast<float4*>(&sB[r * SR + hb]) = acc;
    }
    __syncthreads();
    // ---- phase 6: xf = relu(Ahat @ t2 + bg2) -> sA ----
    {
      float4 acc = *reinterpret_cast<const float4*>(&sBg2[hb]);
      #pragma unroll 8
      for (int p = 0; p < 32; ++p) {
        float a = sAhat[r * 32 + p];
        float4 tv = *reinterpret_cast<const float4*>(&sB[p * SR + hb]);
        acc.x += a * tv.x; acc.y += a * tv.y; acc.z += a * tv.z; acc.w += a * tv.w;
      }
      float4 o = make_float4(fmaxf(acc.x, 0.f), fmaxf(acc.y, 0.f), fmaxf(acc.z, 0.f), fmaxf(acc.w, 0.f));
      *reinterpret_cast<float4*>(&sA[r * SR + hb]) = o;
    }
    __syncthreads();
    // ---- phase 7: LSTM cell ----
    {
      float acc[4][4];
      #pragma unroll
      for (int g = 0; g < 4; ++g) {
        float4 bi = *reinterpret_cast<const float4*>(&sBih[g * 64 + hb]);
        acc[g][0] = bi.x; acc[g][1] = bi.y; acc[g][2] = bi.z; acc[g][3] = bi.w;
      }
      const float* rows[2] = { &sA[r * SR], &sH[cur][r * SR] };
      #pragma unroll
      for (int half = 0; half < 2; ++half) {
        const float* row = rows[half];
        const int kkb = half * 32;
        #pragma unroll 4
        for (int kk = 0; kk < 32; ++kk) {
          const float2 xv = *reinterpret_cast<const float2*>(&row[2 * kk]);
          const unsigned* wp = &sWcat[(kkb + kk) * 256 + hb];
          #pragma unroll
          for (int g = 0; g < 4; ++g) {
            const uint4 w = *reinterpret_cast<const uint4*>(wp + g * 64);
            acc[g][0] += xv.x * bflo(w.x) + xv.y * bfhi(w.x);
            acc[g][1] += xv.x * bflo(w.y) + xv.y * bfhi(w.y);
            acc[g][2] += xv.x * bflo(w.z) + xv.y * bfhi(w.z);
            acc[g][3] += xv.x * bflo(w.w) + xv.y * bfhi(w.w);
          }
        }
      }
      const int nxt = cur ^ 1;
      float4 hv;
      {
        float c0 = sigm(acc[1][0]) * cx[0] + sigm(acc[0][0]) * tanh_fast(acc[2][0]);
        float c1 = sigm(acc[1][1]) * cx[1] + sigm(acc[0][1]) * tanh_fast(acc[2][1]);
        float c2 = sigm(acc[1][2]) * cx[2] + sigm(acc[0][2]) * tanh_fast(acc[2][2]);
        float c3 = sigm(acc[1][3]) * cx[3] + sigm(acc[0][3]) * tanh_fast(acc[2][3]);
        cx[0] = c0; cx[1] = c1; cx[2] = c2; cx[3] = c3;
        hv.x = sigm(acc[3][0]) * tanh_fast(c0);
        hv.y = sigm(acc[3][1]) * tanh_fast(c1);
        hv.z = sigm(acc[3][2]) * tanh_fast(c2);
        hv.w = sigm(acc[3][3]) * tanh_fast(c3);
      }
      *reinterpret_cast<float4*>(&sH[nxt][r * SR + hb]) = hv;
      cur = nxt;
    }
    __syncthreads();
    // ---- decoder head ----
    if (dec) {
      {
        const int mb = (tid & 15) * 2;
        float ax = sBd1[mb], ay = sBd1[mb + 1];
        const float* hrow = &sH[cur][r * SR];
        #pragma unroll 8
        for (int k = 0; k < 64; ++k) {
          float x = hrow[k];
          float2 w = *reinterpret_cast<const float2*>(&sWd1[k * 32 + mb]);
          ax += x * w.x; ay += x * w.y;
        }
        sD1[r * DSR + mb]     = fmaxf(ax, 0.f);
        sD1[r * DSR + mb + 1] = fmaxf(ay, 0.f);
      }
      __syncthreads();
      if (tid < 192) {
        int j = tid / 6, d = tid - j * 6;
        float acc = sBd2[d];
        #pragma unroll 8
        for (int m = 0; m < 32; ++m) acc += sD1[j * DSR + m] * sWd2[m * 6 + d];
        float p = sX[j * 12 + d] + acc;
        sX[j * 12 + d] = p;
        out[(((long long)b * FUT + (step - TSTEPS)) * 32 + j) * 6 + d] = p;
      }
      __syncthreads();
    }
  }
}

extern "C" void kernel_launch(void* const* d_in, const int* in_sizes, int n_in,
                              void* d_out, int out_size, void* d_ws, size_t ws_size,
                              hipStream_t stream) {
  (void)in_sizes; (void)n_in; (void)d_ws; (void)ws_size; (void)out_size;
  const float* xh   = (const float*)d_in[0];
  const float* adj  = (const float*)d_in[1];
  const float* Wenc = (const float*)d_in[2];
  const float* benc = (const float*)d_in[3];
  const float* Wg1  = (const float*)d_in[4];
  const float* bg1  = (const float*)d_in[5];
  const float* Wg2  = (const float*)d_in[6];
  const float* bg2  = (const float*)d_in[7];
  const float* Wih  = (const float*)d_in[8];
  const float* Whh  = (const float*)d_in[9];
  const float* bih  = (const float*)d_in[10];
  const float* bhh  = (const float*)d_in[11];
  const float* Wd1  = (const float*)d_in[12];
  const float* bd1  = (const float*)d_in[13];
  const float* Wd2  = (const float*)d_in[14];
  const float* bd2  = (const float*)d_in[15];
  float* out = (float*)d_out;
  stgnn_kernel<<<dim3(2048), dim3(NT), 0, stream>>>(
      xh, adj, Wenc, benc, Wg1, bg1, Wg2, bg2,
      Wih, Whh, bih, bhh, Wd1, bd1, Wd2, bd2, out);
}

// Round 2
// 4340.152 us; speedup vs baseline: 3.9541x; 3.9541x over previous
//
#include <hip/hip_runtime.h>
#include <cstdint>

// WeatherSTGNN persistent kernel, round 2: MFMA for the big GEMMs.
// One block = one batch element, 96 sequential steps. 8 waves (512 thr).
// MFMA (bf16 32x32x16): ph3 t1=enc@Wg1 (2 waves), ph5 t2=s1@Wg2 (2 waves),
// LSTM g=[xf|h]@Wcat (8 waves, K=128), dec1 d1=h@Wd1 (1 wave).
// VALU fp32: ph2 encoder-in, ph4/ph6 Ahat mixes (reads fp32 sT scratch),
// LSTM nonlinearity (cx in regs), dec2. Weights pre-staged in fragment-linear
// bf16 LDS so B-frag loads are contiguous ds_read_b128. A and B frags share
// the same k-convention, so k-permutation assumptions cancel; C/D layout is
// the HW-verified col=lane&31, row=(reg&3)+8*(reg>>2)+4*(lane>>5).

#define NT 512
#define TSTEPS 48
#define FUT 48
#define ST 68     // sT fp32 stride
#define GS 272    // sG fp32 stride; 272 % 32 == 16 -> conflict-free float4 reads
#define DSR 33

typedef __bf16 bf16;
typedef __attribute__((ext_vector_type(4))) __bf16 bf16x4;
typedef __attribute__((ext_vector_type(8))) __bf16 bf16x8;
typedef __attribute__((ext_vector_type(16))) float f32x16;

__device__ __forceinline__ float sigm(float x) { return 1.0f / (1.0f + __expf(-x)); }
__device__ __forceinline__ float tanh_fast(float x) { return 1.0f - 2.0f / (__expf(2.0f * x) + 1.0f); }

// A-frag linear index for M=32 tile: element (m, k)
__device__ __forceinline__ int aidx(int m, int k) {
  return (((k >> 4) * 64) + m + 32 * ((k >> 3) & 1)) * 8 + (k & 7);
}
// B-frag linear index: element (k, n), Kc = K/16 chunks
__device__ __forceinline__ int bidx(int k, int n, int Kc) {
  return ((((n >> 5) * Kc + (k >> 4)) * 64) + (n & 31) + 32 * ((k >> 3) & 1)) * 8 + (k & 7);
}

__global__ __launch_bounds__(NT, 1)
void stgnn_kernel(const float* __restrict__ xh, const float* __restrict__ adj,
                  const float* __restrict__ Wenc, const float* __restrict__ benc,
                  const float* __restrict__ Wg1, const float* __restrict__ bg1,
                  const float* __restrict__ Wg2, const float* __restrict__ bg2,
                  const float* __restrict__ Wih, const float* __restrict__ Whh,
                  const float* __restrict__ bih, const float* __restrict__ bhh,
                  const float* __restrict__ Wd1, const float* __restrict__ bd1,
                  const float* __restrict__ Wd2, const float* __restrict__ bd2,
                  float* __restrict__ out) {
  // fp32 weights/misc
  __shared__ __align__(16) float sWenc[11 * 64];
  __shared__ __align__(16) float sBenc[64];
  __shared__ __align__(16) float sBg1[64];
  __shared__ __align__(16) float sBg2[64];
  __shared__ __align__(16) float sAhat[32 * 32];
  __shared__ __align__(16) float sBih[256];
  __shared__ __align__(16) float sBd1[32];
  __shared__ __align__(16) float sWd2[32 * 6];
  __shared__ __align__(16) float sBd2[8];
  __shared__ float sDeg[32];
  __shared__ __align__(16) float sX[32 * 12];
  // bf16 fragment-linear weights
  __shared__ __align__(16) bf16 sWg1B[64 * 64];
  __shared__ __align__(16) bf16 sWg2B[64 * 64];
  __shared__ __align__(16) bf16 sWcatB[128 * 256];
  __shared__ __align__(16) bf16 sWd1B[64 * 32];
  // bf16 fragment-linear activations
  __shared__ __align__(16) bf16 sActA1[32 * 64];     // enc / s1 (A for ph3/ph5)
  __shared__ __align__(16) bf16 sActA2[32 * 128];    // [xf | h]  (A for LSTM; h half = A for dec1)
  // fp32 scratch
  __shared__ __align__(16) float sT[32 * ST];        // t1 / t2
  __shared__ __align__(16) float sG[32 * GS];        // LSTM pre-activations
  __shared__ __align__(16) float sD1[32 * DSR];

  const int tid = threadIdx.x;
  const int b = blockIdx.x;
  const int lane = tid & 63;
  const int wv = tid >> 6;
  const int r = tid >> 4;           // node row 0..31
  const int hb = (tid & 15) << 2;   // h base 0,4,...,60

  // ---------------- stage weights ----------------
  for (int i = tid; i < 11 * 64; i += NT) sWenc[i] = Wenc[i];
  for (int i = tid; i < 64; i += NT) { sBenc[i] = benc[i]; sBg1[i] = bg1[i]; sBg2[i] = bg2[i]; }
  for (int i = tid; i < 256; i += NT) sBih[i] = bih[i] + bhh[i];
  for (int i = tid; i < 32; i += NT) sBd1[i] = bd1[i];
  for (int i = tid; i < 32 * 6; i += NT) sWd2[i] = Wd2[i];
  if (tid < 8) sBd2[tid] = (tid < 6) ? bd2[tid] : 0.0f;
  // B-frag weights
  for (int i = tid; i < 64 * 64; i += NT) {
    int k = i >> 6, n = i & 63;
    sWg1B[bidx(k, n, 4)] = (bf16)Wg1[i];
    sWg2B[bidx(k, n, 4)] = (bf16)Wg2[i];
  }
  for (int i = tid; i < 128 * 256; i += NT) {
    int k = i >> 8, n = i & 255;
    float v = (k < 64) ? Wih[n * 64 + k] : Whh[n * 64 + (k - 64)];
    sWcatB[bidx(k, n, 8)] = (bf16)v;
  }
  for (int i = tid; i < 64 * 32; i += NT) {
    int k = i >> 5, n = i & 31;
    sWd1B[bidx(k, n, 4)] = (bf16)Wd1[i];
  }
  for (int i = tid; i < 32 * 128; i += NT) sActA2[i] = (bf16)0.0f;  // h(0) = 0
  if (tid < 32) {
    float s = 0.0f;
    for (int j = 0; j < 32; ++j) s += (j == tid) ? 1.0f : adj[tid * 32 + j];
    sDeg[tid] = 1.0f / sqrtf(fmaxf(s, 1.0f));
  }
  __syncthreads();
  for (int i = tid; i < 32 * 32; i += NT) {
    int ii = i >> 5, jj = i & 31;
    float v = (ii == jj) ? 1.0f : adj[i];
    sAhat[i] = sDeg[ii] * v * sDeg[jj];
  }
  float cx[4] = {0.0f, 0.0f, 0.0f, 0.0f};
  __syncthreads();

  for (int step = 0; step < TSTEPS + FUT; ++step) {
    const bool dec = (step >= TSTEPS);
    // ---- phase 1 (encoder only): load x_t -> sX ----
    if (!dec) {
      if (tid < 32 * 11) {
        int j = tid / 11, f = tid - j * 11;
        sX[j * 12 + f] = xh[(((long long)b * TSTEPS + step) * 32 + j) * 11 + f];
      }
      __syncthreads();
    }
    // ---- phase 2 (VALU): enc = relu(x @ Wenc + benc) -> sActA1 (bf16 A-frag) ----
    {
      float4 acc = *reinterpret_cast<const float4*>(&sBenc[hb]);
      #pragma unroll
      for (int k = 0; k < 11; ++k) {
        float x = sX[r * 12 + k];
        float4 w = *reinterpret_cast<const float4*>(&sWenc[k * 64 + hb]);
        acc.x += x * w.x; acc.y += x * w.y; acc.z += x * w.z; acc.w += x * w.w;
      }
      bf16x4 o = { (bf16)fmaxf(acc.x, 0.f), (bf16)fmaxf(acc.y, 0.f),
                   (bf16)fmaxf(acc.z, 0.f), (bf16)fmaxf(acc.w, 0.f) };
      *reinterpret_cast<bf16x4*>(&sActA1[aidx(r, hb)]) = o;
    }
    __syncthreads();
    // ---- phase 3 (MFMA, waves 0-1): t1 = enc @ Wg1 -> sT (fp32) ----
    if (wv < 2) {
      f32x16 c;
      #pragma unroll
      for (int i = 0; i < 16; ++i) c[i] = 0.0f;
      #pragma unroll
      for (int ch = 0; ch < 4; ++ch) {
        bf16x8 a = *reinterpret_cast<const bf16x8*>(&sActA1[(ch * 64 + lane) * 8]);
        bf16x8 bv = *reinterpret_cast<const bf16x8*>(&sWg1B[((wv * 4 + ch) * 64 + lane) * 8]);
        c = __builtin_amdgcn_mfma_f32_32x32x16_bf16(a, bv, c, 0, 0, 0);
      }
      const int col = wv * 32 + (lane & 31), hf = (lane >> 5) * 4;
      #pragma unroll
      for (int g = 0; g < 4; ++g)
        #pragma unroll
        for (int i = 0; i < 4; ++i)
          sT[(8 * g + hf + i) * ST + col] = c[4 * g + i];
    }
    __syncthreads();
    // ---- phase 4 (VALU): s1 = relu(Ahat @ t1 + bg1) -> sActA1 ----
    {
      float4 acc = *reinterpret_cast<const float4*>(&sBg1[hb]);
      #pragma unroll 8
      for (int p = 0; p < 32; ++p) {
        float a = sAhat[r * 32 + p];
        float4 tv = *reinterpret_cast<const float4*>(&sT[p * ST + hb]);
        acc.x += a * tv.x; acc.y += a * tv.y; acc.z += a * tv.z; acc.w += a * tv.w;
      }
      bf16x4 o = { (bf16)fmaxf(acc.x, 0.f), (bf16)fmaxf(acc.y, 0.f),
                   (bf16)fmaxf(acc.z, 0.f), (bf16)fmaxf(acc.w, 0.f) };
      *reinterpret_cast<bf16x4*>(&sActA1[aidx(r, hb)]) = o;
    }
    __syncthreads();
    // ---- phase 5 (MFMA, waves 0-1): t2 = s1 @ Wg2 -> sT ----
    if (wv < 2) {
      f32x16 c;
      #pragma unroll
      for (int i = 0; i < 16; ++i) c[i] = 0.0f;
      #pragma unroll
      for (int ch = 0; ch < 4; ++ch) {
        bf16x8 a = *reinterpret_cast<const bf16x8*>(&sActA1[(ch * 64 + lane) * 8]);
        bf16x8 bv = *reinterpret_cast<const bf16x8*>(&sWg2B[((wv * 4 + ch) * 64 + lane) * 8]);
        c = __builtin_amdgcn_mfma_f32_32x32x16_bf16(a, bv, c, 0, 0, 0);
      }
      const int col = wv * 32 + (lane & 31), hf = (lane >> 5) * 4;
      #pragma unroll
      for (int g = 0; g < 4; ++g)
        #pragma unroll
        for (int i = 0; i < 4; ++i)
          sT[(8 * g + hf + i) * ST + col] = c[4 * g + i];
    }
    __syncthreads();
    // ---- phase 6 (VALU): xf = relu(Ahat @ t2 + bg2) -> sActA2 k=0..63 ----
    {
      float4 acc = *reinterpret_cast<const float4*>(&sBg2[hb]);
      #pragma unroll 8
      for (int p = 0; p < 32; ++p) {
        float a = sAhat[r * 32 + p];
        float4 tv = *reinterpret_cast<const float4*>(&sT[p * ST + hb]);
        acc.x += a * tv.x; acc.y += a * tv.y; acc.z += a * tv.z; acc.w += a * tv.w;
      }
      bf16x4 o = { (bf16)fmaxf(acc.x, 0.f), (bf16)fmaxf(acc.y, 0.f),
                   (bf16)fmaxf(acc.z, 0.f), (bf16)fmaxf(acc.w, 0.f) };
      *reinterpret_cast<bf16x4*>(&sActA2[aidx(r, hb)]) = o;
    }
    __syncthreads();
    // ---- phase 7 (MFMA, all 8 waves): g = [xf|h] @ Wcat -> sG (fp32) ----
    {
      f32x16 c;
      #pragma unroll
      for (int i = 0; i < 16; ++i) c[i] = 0.0f;
      #pragma unroll
      for (int ch = 0; ch < 8; ++ch) {
        bf16x8 a = *reinterpret_cast<const bf16x8*>(&sActA2[(ch * 64 + lane) * 8]);
        bf16x8 bv = *reinterpret_cast<const bf16x8*>(&sWcatB[((wv * 8 + ch) * 64 + lane) * 8]);
        c = __builtin_amdgcn_mfma_f32_32x32x16_bf16(a, bv, c, 0, 0, 0);
      }
      const int col = wv * 32 + (lane & 31), hf = (lane >> 5) * 4;
      #pragma unroll
      for (int g = 0; g < 4; ++g)
        #pragma unroll
        for (int i = 0; i < 4; ++i)
          sG[(8 * g + hf + i) * GS + col] = c[4 * g + i];
    }
    __syncthreads();
    // ---- phase 8 (VALU): LSTM nonlinearity; h -> sActA2 k=64..127, cx in regs ----
    {
      float4 gi = *reinterpret_cast<const float4*>(&sG[r * GS + 0 + hb]);
      float4 gf = *reinterpret_cast<const float4*>(&sG[r * GS + 64 + hb]);
      float4 gg = *reinterpret_cast<const float4*>(&sG[r * GS + 128 + hb]);
      float4 go = *reinterpret_cast<const float4*>(&sG[r * GS + 192 + hb]);
      float4 bi = *reinterpret_cast<const float4*>(&sBih[0 + hb]);
      float4 bf = *reinterpret_cast<const float4*>(&sBih[64 + hb]);
      float4 bg = *reinterpret_cast<const float4*>(&sBih[128 + hb]);
      float4 bo = *reinterpret_cast<const float4*>(&sBih[192 + hb]);
      gi.x += bi.x; gi.y += bi.y; gi.z += bi.z; gi.w += bi.w;
      gf.x += bf.x; gf.y += bf.y; gf.z += bf.z; gf.w += bf.w;
      gg.x += bg.x; gg.y += bg.y; gg.z += bg.z; gg.w += bg.w;
      go.x += bo.x; go.y += bo.y; go.z += bo.z; go.w += bo.w;
      float c0 = sigm(gf.x) * cx[0] + sigm(gi.x) * tanh_fast(gg.x);
      float c1 = sigm(gf.y) * cx[1] + sigm(gi.y) * tanh_fast(gg.y);
      float c2 = sigm(gf.z) * cx[2] + sigm(gi.z) * tanh_fast(gg.z);
      float c3 = sigm(gf.w) * cx[3] + sigm(gi.w) * tanh_fast(gg.w);
      cx[0] = c0; cx[1] = c1; cx[2] = c2; cx[3] = c3;
      float h0 = sigm(go.x) * tanh_fast(c0);
      float h1 = sigm(go.y) * tanh_fast(c1);
      float h2 = sigm(go.z) * tanh_fast(c2);
      float h3 = sigm(go.w) * tanh_fast(c3);
      bf16x4 hv = { (bf16)h0, (bf16)h1, (bf16)h2, (bf16)h3 };
      *reinterpret_cast<bf16x4*>(&sActA2[aidx(r, 64 + hb)]) = hv;
    }
    __syncthreads();
    // ---- decoder ----
    if (dec) {
      // dec1 (MFMA, wave 0): d1 = relu(h @ Wd1 + bd1) -> sD1 (fp32)
      if (wv == 0) {
        f32x16 c;
        #pragma unroll
        for (int i = 0; i < 16; ++i) c[i] = 0.0f;
        #pragma unroll
        for (int ch = 0; ch < 4; ++ch) {
          bf16x8 a = *reinterpret_cast<const bf16x8*>(&sActA2[((4 + ch) * 64 + lane) * 8]);
          bf16x8 bv = *reinterpret_cast<const bf16x8*>(&sWd1B[(ch * 64 + lane) * 8]);
          c = __builtin_amdgcn_mfma_f32_32x32x16_bf16(a, bv, c, 0, 0, 0);
        }
        const int col = lane & 31, hf = (lane >> 5) * 4;
        const float bb = sBd1[col];
        #pragma unroll
        for (int g = 0; g < 4; ++g)
          #pragma unroll
          for (int i = 0; i < 4; ++i)
            sD1[(8 * g + hf + i) * DSR + col] = fmaxf(c[4 * g + i] + bb, 0.f);
      }
      __syncthreads();
      // dec2 (VALU): res = d1 @ Wd2 + bd2; pred += res; write out
      if (tid < 192) {
        int j = tid / 6, d = tid - j * 6;
        float acc = sBd2[d];
        #pragma unroll 8
        for (int m = 0; m < 32; ++m) acc += sD1[j * DSR + m] * sWd2[m * 6 + d];
        float p = sX[j * 12 + d] + acc;
        sX[j * 12 + d] = p;
        out[(((long long)b * FUT + (step - TSTEPS)) * 32 + j) * 6 + d] = p;
      }
      __syncthreads();
    }
  }
}

extern "C" void kernel_launch(void* const* d_in, const int* in_sizes, int n_in,
                              void* d_out, int out_size, void* d_ws, size_t ws_size,
                              hipStream_t stream) {
  (void)in_sizes; (void)n_in; (void)d_ws; (void)ws_size; (void)out_size;
  const float* xh   = (const float*)d_in[0];
  const float* adj  = (const float*)d_in[1];
  const float* Wenc = (const float*)d_in[2];
  const float* benc = (const float*)d_in[3];
  const float* Wg1  = (const float*)d_in[4];
  const float* bg1  = (const float*)d_in[5];
  const float* Wg2  = (const float*)d_in[6];
  const float* bg2  = (const float*)d_in[7];
  const float* Wih  = (const float*)d_in[8];
  const float* Whh  = (const float*)d_in[9];
  const float* bih  = (const float*)d_in[10];
  const float* bhh  = (const float*)d_in[11];
  const float* Wd1  = (const float*)d_in[12];
  const float* bd1  = (const float*)d_in[13];
  const float* Wd2  = (const float*)d_in[14];
  const float* bd2  = (const float*)d_in[15];
  float* out = (float*)d_out;
  stgnn_kernel<<<dim3(2048), dim3(NT), 0, stream>>>(
      xh, adj, Wenc, benc, Wg1, bg1, Wg2, bg2,
      Wih, Whh, bih, bhh, Wd1, bd1, Wd2, bd2, out);
}

// Round 3
// 2790.845 us; speedup vs baseline: 6.1492x; 1.5551x over previous
//
#include <hip/hip_runtime.h>
#include <cstdint>

// WeatherSTGNN persistent kernel, round 3.
// 2 batch elements per block (grid 1024 x 1024 threads, 16 waves = 4/SIMD).
// Whole spatial+LSTM chain on MFMA (bf16 32x32x16); Ahat held hi/lo-split in
// 16 VGPRs (exact mix to ~2^-16 on Ahat); every MFMA C written directly into
// the next op's fragment layout (b64 packed where next-K == this-M, b16
// scatter for the two unavoidable transposes). Per-batch activation buffers
// time-aliased in one 16.5KB region (enc/t1/s1/t2 frags (+) sG-bf16 (+) sD1).
// LDS ~145KB -> 1 block/CU but 16 waves. aidx/bidx conventions identical to
// the round-2 kernel (pass-verified); C/D row map col=lane&31,
// row=(reg&3)+8*(reg>>2)+4*(lane>>5).

#define NT 1024
#define TSTEPS 48
#define FUT 48

typedef __bf16 bf16;
typedef __attribute__((ext_vector_type(4))) __bf16 bf16x4;
typedef __attribute__((ext_vector_type(8))) __bf16 bf16x8;
typedef __attribute__((ext_vector_type(16))) float f32x16;

__device__ __forceinline__ float sigm(float x) { return 1.0f / (1.0f + __expf(-x)); }
__device__ __forceinline__ float tanh_fast(float x) { return 1.0f - 2.0f / (__expf(2.0f * x) + 1.0f); }

__global__ __launch_bounds__(NT, 4)
void stgnn_kernel(const float* __restrict__ xh, const float* __restrict__ adj,
                  const float* __restrict__ Wenc, const float* __restrict__ benc,
                  const float* __restrict__ Wg1, const float* __restrict__ bg1,
                  const float* __restrict__ Wg2, const float* __restrict__ bg2,
                  const float* __restrict__ Wih, const float* __restrict__ Whh,
                  const float* __restrict__ bih, const float* __restrict__ bhh,
                  const float* __restrict__ Wd1, const float* __restrict__ bd1,
                  const float* __restrict__ Wd2, const float* __restrict__ bd2,
                  float* __restrict__ out) {
  // ---- shared ----
  __shared__ __align__(16) char  sRegion[2][16896];   // per-batch aliased region
  __shared__ __align__(16) bf16  xfhF2[2][4096];      // [xf(k0..63) | h(k64..127)] A-frag
  __shared__ __align__(16) float sX2[2][2][384];      // [batch][buf][32*12]
  __shared__ __align__(16) bf16  wcatF[32768];        // Wih|Whh B-frag (Kc=8, N=256)
  __shared__ __align__(16) bf16  wg1F[4096];          // Wg1 B-frag (Kc=4, N=64)
  __shared__ __align__(16) bf16  wg2F[4096];          // Wg2^T A-frag (2 M-tiles, Kc=4)
  __shared__ __align__(16) bf16  wd1F[2048];          // Wd1 B-frag (Kc=4, N=32)
  __shared__ __align__(16) float sWenc[704];
  __shared__ __align__(16) float sBenc[64];
  __shared__ __align__(16) float sBg1[64];
  __shared__ __align__(16) float sBg2[64];
  __shared__ __align__(16) float sBih[256];
  __shared__ __align__(16) float sBd1[32];
  __shared__ __align__(16) float sWd2[192];
  __shared__ __align__(16) float sBd2[8];
  __shared__ float sDeg[32];

  const int tid  = threadIdx.x;
  const int bh   = tid >> 9;        // batch half 0/1
  const int lt   = tid & 511;
  const int lane = tid & 63;
  const int lw   = lt >> 6;         // local wave 0..7 within batch
  const int r    = lt >> 4;         // node row 0..31
  const int hb   = (lt & 15) << 2;  // h base 0,4,...,60
  const int hf4  = (lane >> 5) * 4;
  const long long b = (long long)blockIdx.x * 2 + bh;

  // per-batch region pointers (time-aliased)
  bf16*  encF = (bf16*)(sRegion[bh] + 0);      // 32x64  A-frag (4KB)
  bf16*  t1F  = (bf16*)(sRegion[bh] + 4096);   // t1^T A-frag, 2 M-tiles (4KB)
  bf16*  s1F  = (bf16*)(sRegion[bh] + 8192);   // s1 B-frag Kc=4 (4KB)
  bf16*  t2F  = (bf16*)(sRegion[bh] + 12288);  // t2 B-frag Kc=2,N=64 (4KB)
  bf16*  sGb  = (bf16*)(sRegion[bh]);          // 32 x 264 bf16 (16.9KB)
  float* sD1b = (float*)(sRegion[bh]);         // 32 x 36 fp32 (4.6KB)
  bf16*  xfhF = xfhF2[bh];

  // spatial-phase wave assignment: batch0 -> waves 0,1 (SIMD 0,1),
  // batch1 -> waves 10,11 (SIMD 2,3)
  const bool isSpat = (bh == 0) ? (lw < 2) : (lw == 2 || lw == 3);
  const int  sw     = (bh == 0) ? lw : (lw - 2);
  const bool isDec1 = (bh == 0) ? (lw == 4) : (lw == 6);

  // ---------------- stage weights ----------------
  for (int i = tid; i < 704; i += NT) sWenc[i] = Wenc[i];
  for (int i = tid; i < 64; i += NT) { sBenc[i] = benc[i]; sBg1[i] = bg1[i]; sBg2[i] = bg2[i]; }
  for (int i = tid; i < 256; i += NT) sBih[i] = bih[i] + bhh[i];
  for (int i = tid; i < 32; i += NT) sBd1[i] = bd1[i];
  for (int i = tid; i < 192; i += NT) sWd2[i] = Wd2[i];
  if (tid < 8) sBd2[tid] = (tid < 6) ? bd2[tid] : 0.0f;
  for (int i = tid; i < 4096; i += NT) {
    int k = i >> 6, n = i & 63;
    wg1F[((((n >> 5) * 4 + (k >> 4)) * 64) + (n & 31) + 32 * ((k >> 3) & 1)) * 8 + (k & 7)] = (bf16)Wg1[i];
    // Wg2^T A-frag: value Wg2[k(h1)][m(h2)] at tile m>>5
    int m = n;  // reuse loop vars: m = h2, k = h1
    wg2F[(m >> 5) * 2048 + (((k >> 4) * 64) + (m & 31) + 32 * ((k >> 3) & 1)) * 8 + (k & 7)] = (bf16)Wg2[k * 64 + m];
  }
  for (int i = tid; i < 32768; i += NT) {
    int k = i >> 8, n = i & 255;
    float v = (k < 64) ? Wih[n * 64 + k] : Whh[n * 64 + (k - 64)];
    wcatF[((((n >> 5) * 8 + (k >> 4)) * 64) + (n & 31) + 32 * ((k >> 3) & 1)) * 8 + (k & 7)] = (bf16)v;
  }
  for (int i = tid; i < 2048; i += NT) {
    int k = i >> 5, n = i & 31;
    wd1F[(((k >> 4) * 64) + n + 32 * ((k >> 3) & 1)) * 8 + (k & 7)] = (bf16)Wd1[i];
  }
  if (tid < 32) {
    float s = 0.0f;
    for (int j = 0; j < 32; ++j) s += (j == tid) ? 1.0f : adj[tid * 32 + j];
    sDeg[tid] = 1.0f / sqrtf(fmaxf(s, 1.0f));
  }
  __syncthreads();
  // Ahat fp32 scratch in region[0]
  float* AhatS = (float*)(sRegion[0]);
  for (int i = tid; i < 1024; i += NT) {
    int ii = i >> 5, jj = i & 31;
    float v = (ii == jj) ? 1.0f : adj[i];
    AhatS[i] = sDeg[ii] * v * sDeg[jj];
  }
  __syncthreads();
  // per-lane Ahat fragments, hi/lo split (identical A-frag / B-frag(Ahat^T) map)
  bf16x8 ahHi[2], ahLo[2];
  #pragma unroll
  for (int c = 0; c < 2; ++c)
    #pragma unroll
    for (int j = 0; j < 8; ++j) {
      int k = 16 * c + 8 * (lane >> 5) + j;
      float v = AhatS[(lane & 31) * 32 + k];
      bf16 hi = (bf16)v;
      ahHi[c][j] = hi;
      ahLo[c][j] = (bf16)(v - (float)hi);
    }
  // zero h-half of xfh A-frag (h(0)=0)
  for (int i = lt; i < 2048; i += 512) xfhF[2048 + i] = (bf16)0.0f;
  // load x step 0
  if (lt < 352) {
    int j = lt / 11, f = lt - j * 11;
    sX2[bh][0][j * 12 + f] = xh[((b * TSTEPS + 0) * 32 + j) * 11 + f];
  }
  float cx[4] = {0.0f, 0.0f, 0.0f, 0.0f};
  __syncthreads();

  for (int step = 0; step < TSTEPS + FUT; ++step) {
    const bool de = (step >= TSTEPS);
    const int  sb = step & 1;
    float* sXc = de ? sX2[bh][1] : sX2[bh][sb];
    // ---- ph2 (VALU, all): enc = relu(x @ Wenc + benc) -> encF A-frag;
    //      plus next-step x prefetch into the other sX buffer
    {
      float4 acc = *reinterpret_cast<const float4*>(&sBenc[hb]);
      #pragma unroll
      for (int k = 0; k < 11; ++k) {
        float x = sXc[r * 12 + k];
        float4 w = *reinterpret_cast<const float4*>(&sWenc[k * 64 + hb]);
        acc.x += x * w.x; acc.y += x * w.y; acc.z += x * w.z; acc.w += x * w.w;
      }
      bf16x4 o = { (bf16)fmaxf(acc.x, 0.f), (bf16)fmaxf(acc.y, 0.f),
                   (bf16)fmaxf(acc.z, 0.f), (bf16)fmaxf(acc.w, 0.f) };
      *reinterpret_cast<bf16x4*>(&encF[(((hb >> 4) * 64) + r + 32 * ((hb >> 3) & 1)) * 8 + (hb & 7)]) = o;
      if (!de && step < TSTEPS - 1 && lt < 352) {
        int j = lt / 11, f = lt - j * 11;
        sX2[bh][sb ^ 1][j * 12 + f] = xh[((b * TSTEPS + step + 1) * 32 + j) * 11 + f];
      }
    }
    __syncthreads();  // B1
    // ---- T1 (MFMA, spatial waves): t1 = enc @ Wg1 ; C -> t1F (t1^T A-frag, packed b64)
    if (isSpat) {
      f32x16 c;
      #pragma unroll
      for (int i = 0; i < 16; ++i) c[i] = 0.0f;
      #pragma unroll
      for (int ch = 0; ch < 4; ++ch) {
        bf16x8 a  = *reinterpret_cast<const bf16x8*>(&encF[(ch * 64 + lane) * 8]);
        bf16x8 bv = *reinterpret_cast<const bf16x8*>(&wg1F[((sw * 4 + ch) * 64 + lane) * 8]);
        c = __builtin_amdgcn_mfma_f32_32x32x16_bf16(a, bv, c, 0, 0, 0);
      }
      #pragma unroll
      for (int g = 0; g < 4; ++g) {
        bf16x4 o = { (bf16)c[4*g], (bf16)c[4*g+1], (bf16)c[4*g+2], (bf16)c[4*g+3] };
        *reinterpret_cast<bf16x4*>(&t1F[sw * 2048 + (((g >> 1) * 64) + (lane & 31) + 32 * (g & 1)) * 8 + hf4]) = o;
      }
    }
    __syncthreads();  // B2
    // ---- S1 (MFMA, spatial): s1^T = t1^T @ Ahat^T (hi+lo), +bg1, relu -> s1F B-frag (b64)
    if (isSpat) {
      f32x16 c;
      #pragma unroll
      for (int i = 0; i < 16; ++i) c[i] = 0.0f;
      #pragma unroll
      for (int ch = 0; ch < 2; ++ch) {
        bf16x8 a = *reinterpret_cast<const bf16x8*>(&t1F[sw * 2048 + (ch * 64 + lane) * 8]);
        c = __builtin_amdgcn_mfma_f32_32x32x16_bf16(a, ahHi[ch], c, 0, 0, 0);
        c = __builtin_amdgcn_mfma_f32_32x32x16_bf16(a, ahLo[ch], c, 0, 0, 0);
      }
      #pragma unroll
      for (int g = 0; g < 4; ++g) {
        bf16 p[4];
        #pragma unroll
        for (int i = 0; i < 4; ++i) {
          int h1 = 32 * sw + 8 * g + hf4 + i;
          p[i] = (bf16)fmaxf(c[4*g+i] + sBg1[h1], 0.f);
        }
        bf16x4 o = { p[0], p[1], p[2], p[3] };
        *reinterpret_cast<bf16x4*>(&s1F[(((2 * sw + (g >> 1)) * 64) + (lane & 31) + 32 * (g & 1)) * 8 + hf4]) = o;
      }
    }
    __syncthreads();  // B3
    // ---- T2 (MFMA, spatial): t2^T = Wg2^T @ s1^T ; C -> t2F (XF B-frag, b16 scatter)
    if (isSpat) {
      f32x16 c;
      #pragma unroll
      for (int i = 0; i < 16; ++i) c[i] = 0.0f;
      #pragma unroll
      for (int ch = 0; ch < 4; ++ch) {
        bf16x8 a  = *reinterpret_cast<const bf16x8*>(&wg2F[sw * 2048 + (ch * 64 + lane) * 8]);
        bf16x8 bv = *reinterpret_cast<const bf16x8*>(&s1F[(ch * 64 + lane) * 8]);
        c = __builtin_amdgcn_mfma_f32_32x32x16_bf16(a, bv, c, 0, 0, 0);
      }
      const int node = lane & 31;
      const int sbase = ((sw * 2 + (node >> 4)) * 64 + 32 * ((node >> 3) & 1)) * 8 + (node & 7);
      #pragma unroll
      for (int ri = 0; ri < 16; ++ri) {
        int rl = (ri & 3) + 8 * (ri >> 2) + hf4;   // h2 local row
        t2F[sbase + rl * 8] = (bf16)c[ri];
      }
    }
    __syncthreads();  // B4
    // ---- XF (MFMA, spatial): xf = Ahat @ t2 (hi+lo), +bg2, relu -> xfhF[k<64] (b16 scatter)
    if (isSpat) {
      f32x16 c;
      #pragma unroll
      for (int i = 0; i < 16; ++i) c[i] = 0.0f;
      #pragma unroll
      for (int ch = 0; ch < 2; ++ch) {
        bf16x8 bv = *reinterpret_cast<const bf16x8*>(&t2F[((sw * 2 + ch) * 64 + lane) * 8]);
        c = __builtin_amdgcn_mfma_f32_32x32x16_bf16(ahHi[ch], bv, c, 0, 0, 0);
        c = __builtin_amdgcn_mfma_f32_32x32x16_bf16(ahLo[ch], bv, c, 0, 0, 0);
      }
      const int h2 = 32 * sw + (lane & 31);
      const float bias = sBg2[h2];
      const int abase = (((h2 >> 4) * 64) + 32 * ((h2 >> 3) & 1)) * 8 + (h2 & 7);
      #pragma unroll
      for (int ri = 0; ri < 16; ++ri) {
        int node = (ri & 3) + 8 * (ri >> 2) + hf4;
        xfhF[abase + node * 8] = (bf16)fmaxf(c[ri] + bias, 0.f);
      }
    }
    __syncthreads();  // B5
    // ---- LSTM (MFMA, all 8 waves/batch): g = [xf|h] @ Wcat -> sGb bf16
    {
      f32x16 c;
      #pragma unroll
      for (int i = 0; i < 16; ++i) c[i] = 0.0f;
      #pragma unroll
      for (int ch = 0; ch < 8; ++ch) {
        bf16x8 a  = *reinterpret_cast<const bf16x8*>(&xfhF[(ch * 64 + lane) * 8]);
        bf16x8 bv = *reinterpret_cast<const bf16x8*>(&wcatF[((lw * 8 + ch) * 64 + lane) * 8]);
        c = __builtin_amdgcn_mfma_f32_32x32x16_bf16(a, bv, c, 0, 0, 0);
      }
      const int col = lw * 32 + (lane & 31);
      #pragma unroll
      for (int ri = 0; ri < 16; ++ri) {
        int node = (ri & 3) + 8 * (ri >> 2) + hf4;
        sGb[node * 264 + col] = (bf16)c[ri];
      }
    }
    __syncthreads();  // B6
    // ---- nonlin (VALU, all): gates -> c,h ; h -> xfhF[k>=64] (b64)
    {
      float g4[4][4];
      #pragma unroll
      for (int gi = 0; gi < 4; ++gi) {
        bf16x4 gv = *reinterpret_cast<const bf16x4*>(&sGb[r * 264 + gi * 64 + hb]);
        float4 bi = *reinterpret_cast<const float4*>(&sBih[gi * 64 + hb]);
        g4[gi][0] = (float)gv[0] + bi.x; g4[gi][1] = (float)gv[1] + bi.y;
        g4[gi][2] = (float)gv[2] + bi.z; g4[gi][3] = (float)gv[3] + bi.w;
      }
      bf16 hp[4];
      #pragma unroll
      for (int i = 0; i < 4; ++i) {
        float cc = sigm(g4[1][i]) * cx[i] + sigm(g4[0][i]) * tanh_fast(g4[2][i]);
        cx[i] = cc;
        hp[i] = (bf16)(sigm(g4[3][i]) * tanh_fast(cc));
      }
      bf16x4 hv = { hp[0], hp[1], hp[2], hp[3] };
      *reinterpret_cast<bf16x4*>(&xfhF[(((4 + (hb >> 4)) * 64) + r + 32 * ((hb >> 3) & 1)) * 8 + (hb & 7)]) = hv;
    }
    __syncthreads();  // B7 (protects sG region before next ph2 rewrites encF)
    if (de) {
      // ---- dec1 (MFMA, 1 wave/batch): d1 = relu(h @ Wd1 + bd1) -> sD1 fp32
      if (isDec1) {
        f32x16 c;
        #pragma unroll
        for (int i = 0; i < 16; ++i) c[i] = 0.0f;
        #pragma unroll
        for (int ch = 0; ch < 4; ++ch) {
          bf16x8 a  = *reinterpret_cast<const bf16x8*>(&xfhF[((4 + ch) * 64 + lane) * 8]);
          bf16x8 bv = *reinterpret_cast<const bf16x8*>(&wd1F[(ch * 64 + lane) * 8]);
          c = __builtin_amdgcn_mfma_f32_32x32x16_bf16(a, bv, c, 0, 0, 0);
        }
        const int col = lane & 31;
        const float bb = sBd1[col];
        #pragma unroll
        for (int ri = 0; ri < 16; ++ri) {
          int node = (ri & 3) + 8 * (ri >> 2) + hf4;
          sD1b[node * 36 + col] = fmaxf(c[ri] + bb, 0.f);
        }
      }
      __syncthreads();  // B8
      // ---- dec2 (VALU): res = d1 @ Wd2 + bd2; pred += res; write out
      if (lt < 192) {
        int j = lt / 6, d = lt - j * 6;
        float acc = sBd2[d];
        #pragma unroll 8
        for (int m = 0; m < 32; ++m) acc += sD1b[j * 36 + m] * sWd2[m * 6 + d];
        float p = sXc[j * 12 + d] + acc;
        sXc[j * 12 + d] = p;
        out[((b * FUT + (step - TSTEPS)) * 32 + j) * 6 + d] = p;
      }
      __syncthreads();  // B9
    }
  }
}

extern "C" void kernel_launch(void* const* d_in, const int* in_sizes, int n_in,
                              void* d_out, int out_size, void* d_ws, size_t ws_size,
                              hipStream_t stream) {
  (void)in_sizes; (void)n_in; (void)d_ws; (void)ws_size; (void)out_size;
  const float* xh   = (const float*)d_in[0];
  const float* adj  = (const float*)d_in[1];
  const float* Wenc = (const float*)d_in[2];
  const float* benc = (const float*)d_in[3];
  const float* Wg1  = (const float*)d_in[4];
  const float* bg1  = (const float*)d_in[5];
  const float* Wg2  = (const float*)d_in[6];
  const float* bg2  = (const float*)d_in[7];
  const float* Wih  = (const float*)d_in[8];
  const float* Whh  = (const float*)d_in[9];
  const float* bih  = (const float*)d_in[10];
  const float* bhh  = (const float*)d_in[11];
  const float* Wd1  = (const float*)d_in[12];
  const float* bd1  = (const float*)d_in[13];
  const float* Wd2  = (const float*)d_in[14];
  const float* bd2  = (const float*)d_in[15];
  float* out = (float*)d_out;
  stgnn_kernel<<<dim3(1024), dim3(NT), 0, stream>>>(
      xh, adj, Wenc, benc, Wg1, bg1, Wg2, bg2,
      Wih, Whh, bih, bhh, Wd1, bd1, Wd2, bd2, out);
}